// Round 5
// baseline (95.436 us; speedup 1.0000x reference)
//
#include <hip/hip_runtime.h>
#include <hip/hip_fp16.h>

#define B 128
#define L 1024
// triangular decomposition: 16 col-segments of 64; 2 row-bands of 512.
// tiles per batch: band0 q=0..15 (tl=q), band1 q=8..15 (tl=q+8). 24 tiles.
#define NTILE 24
#define TSTRIDE 576   // per-tile ws slice: 512 row partials + 64 col partials

#if __has_builtin(__builtin_amdgcn_exp2f)
#define EXP2(x) __builtin_amdgcn_exp2f(x)
#else
#define EXP2(x) __expf((x) * 0.6931471805599453f)
#endif

typedef unsigned int uint4v __attribute__((ext_vector_type(4)));

// ws layout (floats):
//   [0 .. B*24*576)   per-(b,tile) slices: rows[512] then cols[64]
//   [WS_ACC]          ndcg accumulator (zeroed by pair_kernel block 0)
//   [WS_GCTR]         completion counter
#define WS_ACC  (B * NTILE * TSTRIDE)
#define WS_GCTR (WS_ACC + 1)

// erfc(|y|) ~= exp(-(1.12838 y + 0.6446 y^2 + 0.0745 y^3)), |dPhi| <= ~2.5e-4,
// y = diff/2 (prescaled into the f16 row). Constants pre-multiplied by
// -log2(e) so v_exp_f16 computes exp2 directly.
#define K1f -1.6279072f
#define K2f -0.9299637f
#define K3f -0.1074808f

// one packed evaluation: du holds 2 f16 j-values; returns erf(y_i - y_j) x2
// (signed, via v_bfi sign transfer). d==0 gives exactly 0 (e=1, r=0, +0 sign),
// so diagonal elements self-cancel.
__device__ __forceinline__ __half2 term2v(unsigned int du, __half2 pi2,
                                          __half2 k1, __half2 k2, __half2 k3,
                                          __half2 one2) {
    __half2 pj = __builtin_bit_cast(__half2, du);
    __half2 d  = __hsub2(pi2, pj);
    unsigned int dbits = __builtin_bit_cast(unsigned int, d);
    __half2 a  = __builtin_bit_cast(__half2, dbits & 0x7fff7fffu); // |d|
    __half2 t  = __hfma2(k3, a, k2);
    __half2 u  = __hfma2(t,  a, k1);
    __half2 w  = __hmul2(a, u);                      // <= 0
    __half2 e  = __halves2half2(hexp2(__low2half(w)),
                                hexp2(__high2half(w)));   // ~= erfc(|y|)
    __half2 r  = __hsub2(one2, e);                   // >= 0, sign bits clear
    unsigned int rs = (dbits & 0x80008000u)
                    | (__builtin_bit_cast(unsigned int, r) & 0x7fff7fffu);
    return __builtin_bit_cast(__half2, rs);          // erf(y), signed
}

// Antisymmetric (triangular) pair kernel. Block = (b, tile(r,q)).
// Sub-tiles (seg s in band r) x (seg q): s<q -> row+col accumulate;
// s==q -> full 64x64 compute, ROW-ONLY (avoids double count; diag term = 0);
// s>q -> skipped (mirror covered by the (q,s) tile's col path).
// Computed erf work = 136/256 = 53% of the full matrix.
// Col partials accumulate in 8 registers per thread across the <=8 row
// iterations, reduced ONCE per block through LDS (no per-term DS ops).
// Plain disjoint ws stores only — no global atomics here (R6 lesson).
__global__ __launch_bounds__(256, 8) void pair_kernel(const float* __restrict__ preds,
                                                      const float* __restrict__ target,
                                                      float* __restrict__ ws) {
    // sph[1024] f16 | rowLDS f32[8][4][64] | colLDS u32[32][64]
    // col2LDS f32[8][64] aliases sph (sph reads all precede the first barrier
    // after the rr-loop, so the alias is race-free).
    __shared__ __align__(16) unsigned char smem[2048 + 8192 + 8192];
    __half* sph = (__half*)smem;
    float* rowLDS = (float*)(smem + 2048);
    unsigned int* colLDS = (unsigned int*)(smem + 2048 + 8192);
    float* col2LDS = (float*)smem;

    const int blk = blockIdx.x;
    const int b   = blk / NTILE;
    const int tl  = blk - b * NTILE;
    const int r   = (tl >= 16) ? 1 : 0;
    const int q   = r ? (tl - 8) : tl;
    const int tid = threadIdx.x;
    const int il  = tid & 63;
    const int jq  = tid >> 6;

    if (blk == 0 && tid == 0) {
        ws[WS_ACC] = 0.0f;                 // visible to finish at dispatch boundary
        ((int*)ws)[WS_GCTR] = 0;
    }

    // stage full row as f16, prescaled by 0.5 (erf argument is diff/2)
    const float* prow = preds + b * L;
    float4 v4 = reinterpret_cast<const float4*>(prow)[tid];
    reinterpret_cast<__half2*>(sph)[tid * 2 + 0] = __floats2half2_rn(0.5f * v4.x, 0.5f * v4.y);
    reinterpret_cast<__half2*>(sph)[tid * 2 + 1] = __floats2half2_rn(0.5f * v4.z, 0.5f * v4.w);
    __syncthreads();

    const __half2 k1   = __floats2half2_rn(K1f, K1f);
    const __half2 k2   = __floats2half2_rn(K2f, K2f);
    const __half2 k3   = __floats2half2_rn(K3f, K3f);
    const __half2 one2 = __floats2half2_rn(1.0f, 1.0f);
    const __half2 z2   = __floats2half2_rn(0.0f, 0.0f);

    // this thread's 16 j's of seg q (8 half2)
    const uint4v* cp4 = reinterpret_cast<const uint4v*>(sph + q * 64 + jq * 16);
    uint4v pq0 = cp4[0], pq1 = cp4[1];
    unsigned int pjb[8] = {pq0.x, pq0.y, pq0.z, pq0.w, pq1.x, pq1.y, pq1.z, pq1.w};

    __half2 colacc[8] = {z2, z2, z2, z2, z2, z2, z2, z2};

    const int r8 = r << 3;
    for (int rr = 0; rr < 8; ++rr) {       // rows: seg s = 8r+rr (wave-uniform trip)
        const int s = r8 + rr;
        if (s > q) break;
        const bool ca = (s < q);           // col-accumulate? (uniform)
        const __half2 pi2 = __half2half2(sph[(s << 6) + il]);
        __half2 A = z2, Bc = z2;           // two 4-deep row chains (|acc|<=4 in f16)
        #pragma unroll
        for (int m = 0; m < 8; ++m) {
            __half2 tm = term2v(pjb[m], pi2, k1, k2, k3, one2);
            if (m < 4) A = __hadd2(A, tm); else Bc = __hadd2(Bc, tm);
            if (ca) colacc[m] = __hadd2(colacc[m], tm);   // <=8 adds total: f16 ok
        }
        float2 fA = __half22float2(A), fB = __half22float2(Bc);
        rowLDS[(rr << 8) + (jq << 6) + il] = (fA.x + fA.y) + (fB.x + fB.y);
    }

    // park col partials (per-thread, register -> LDS; conflict-free stores)
    #pragma unroll
    for (int m = 0; m < 8; ++m)
        colLDS[((jq << 3) + m) * 64 + il] = __builtin_bit_cast(unsigned int, colacc[m]);
    __syncthreads();

    float* wst = ws + (b * NTILE + tl) * TSTRIDE;

    // row writeout: 2 rows per thread, sum the 4 j-quarters.
    // inactive-rr slices carry garbage but are never read by finish (q>=s only).
    #pragma unroll
    for (int h = 0; h < 2; ++h) {
        int rho = tid + (h << 8);
        int rrx = rho >> 6, ilx = rho & 63;
        float v = (rowLDS[(rrx << 8) + ilx]       + rowLDS[(rrx << 8) + 64 + ilx])
                + (rowLDS[(rrx << 8) + 128 + ilx] + rowLDS[(rrx << 8) + 192 + ilx]);
        wst[rho] = v;
    }

    // col reduce stage 1: thread (cp=tid&31, ilq=tid>>5) sums 8 lanes' half2
    // partials in f32. col-pair cp covers j_local = 2cp{+1}.
    {
        int cp = tid & 31, ilq = tid >> 5;
        const uint4v* cl = reinterpret_cast<const uint4v*>(colLDS + cp * 64 + ilq * 8);
        uint4v c0 = cl[0], c1 = cl[1];
        unsigned int cc[8] = {c0.x, c0.y, c0.z, c0.w, c1.x, c1.y, c1.z, c1.w};
        float sx = 0.0f, sy = 0.0f;
        #pragma unroll
        for (int k = 0; k < 8; ++k) {
            float2 f = __half22float2(__builtin_bit_cast(__half2, cc[k]));
            sx += f.x; sy += f.y;
        }
        col2LDS[ilq * 64 + cp * 2 + 0] = sx;   // [ilq][j_local]
        col2LDS[ilq * 64 + cp * 2 + 1] = sy;
    }
    __syncthreads();

    // col reduce stage 2: thread t<64 owns j_local = t
    if (tid < 64) {
        float cs = 0.0f;
        #pragma unroll
        for (int g = 0; g < 8; ++g) cs += col2LDS[g * 64 + tid];
        wst[512 + tid] = cs;
    }
}

// grid = B blocks, 256 threads. Block b: gather Es from row/col slices,
// DCG tail (moved here from pair), counting-sort IDCG, ndcg; last block
// writes the final scalar.
__global__ __launch_bounds__(256) void finish_kernel(const float* __restrict__ target,
                                                     float* __restrict__ ws,
                                                     float* __restrict__ out) {
    __shared__ unsigned long long cred[256];
    __shared__ float2 fred[256];

    const int b   = blockIdx.x;
    const int tid = threadIdx.x;
    const float* trow = target + b * L;

    // packed 16-bit counts of grades >=4,>=3,>=2,>=1 (max 1024 fits)
    float tv[4];
    unsigned long long cnt = 0ull;
    #pragma unroll
    for (int k = 0; k < 4; ++k) {
        float t = trow[tid + k * 256];
        tv[k] = t;
        cnt += ((unsigned long long)(t > 3.5f) << 48)
             + ((unsigned long long)(t > 2.5f) << 32)
             + ((unsigned long long)(t > 1.5f) << 16)
             + ((unsigned long long)(t > 0.5f));
    }
    cred[tid] = cnt;
    __syncthreads();
    #pragma unroll
    for (int s = 128; s > 0; s >>= 1) {
        if (tid < (unsigned)s) cred[tid] += cred[tid + s];
        __syncthreads();
    }
    unsigned long long tot = cred[0];
    const int n4 = (int)(tot >> 48) & 0xFFFF;
    const int n3 = (int)(tot >> 32) & 0xFFFF;
    const int n2 = (int)(tot >> 16) & 0xFFFF;
    const int n1 = (int)(tot)       & 0xFFFF;

    // parallel IDCG
    float idcg_p = 0.0f;
    #pragma unroll
    for (int k = 0; k < 4; ++k) {
        int pos = tid + 1 + k * 256;
        float gain = (pos <= n4) ? 15.0f : (pos <= n3) ? 7.0f :
                     (pos <= n2) ? 3.0f  : (pos <= n1) ? 1.0f : 0.0f;
        idcg_p += gain * __builtin_amdgcn_rcpf(__log2f((float)pos + 1.0f));
    }

    // DCG: Es(i) = sum_{q>=seg(i)} rowslice(band,q)[rho]
    //            - colslice(band0, seg)[il]  (seg>=1)
    //            - colslice(band1, seg)[il]  (seg>=9)
    // er+1 = 513.5 + Es/2 (diag term is exactly 0).
    const int b24 = b * NTILE;
    float dcg_p = 0.0f;
    #pragma unroll
    for (int k = 0; k < 4; ++k) {
        int i  = tid + (k << 8);
        int u  = i >> 6;           // seg (wave-uniform)
        int rb = u >> 3;           // band
        int rho = i & 511;
        float rowsum = 0.0f;
        for (int qq = u; qq < 16; ++qq)
            rowsum += ws[(b24 + qq + (rb << 3)) * TSTRIDE + rho];
        float cols = 0.0f;
        int i6 = i & 63;
        if (u >= 1) cols += ws[(b24 + u) * TSTRIDE + 512 + i6];
        if (u >= 9) cols += ws[(b24 + u + 8) * TSTRIDE + 512 + i6];
        float Es  = rowsum - cols;
        float er1 = 513.5f + 0.5f * Es;
        float g   = EXP2(tv[k]) - 1.0f;     // 2^t - 1, exact for integer grades
        dcg_p += g * __builtin_amdgcn_rcpf(__log2f(er1));
    }

    fred[tid] = make_float2(idcg_p, dcg_p);
    __syncthreads();
    #pragma unroll
    for (int s = 128; s > 0; s >>= 1) {
        if (tid < (unsigned)s) {
            float2 x = fred[tid], y = fred[tid + s];
            fred[tid] = make_float2(x.x + y.x, x.y + y.y);
        }
        __syncthreads();
    }

    if (tid == 0) {
        float ndcg = fred[0].y / (fred[0].x + 1e-10f);
        atomicAdd(&ws[WS_ACC], ndcg);
        __threadfence();
        int old = atomicAdd((int*)ws + WS_GCTR, 1);
        if (old == B - 1) {
            float acc = atomicAdd(&ws[WS_ACC], 0.0f);  // coherent read
            out[0] = -acc * (1.0f / (float)B);
        }
    }
}

extern "C" void kernel_launch(void* const* d_in, const int* in_sizes, int n_in,
                              void* d_out, int out_size, void* d_ws, size_t ws_size,
                              hipStream_t stream) {
    const float* preds  = (const float*)d_in[0];
    const float* target = (const float*)d_in[1];
    float* out = (float*)d_out;
    float* ws  = (float*)d_ws;

    pair_kernel<<<B * NTILE, 256, 0, stream>>>(preds, target, ws);
    finish_kernel<<<B, 256, 0, stream>>>(target, ws, out);
}

// Round 6
// 89.003 us; speedup vs baseline: 1.0723x; 1.0723x over previous
//
#include <hip/hip_runtime.h>
#include <hip/hip_fp16.h>

#define B 128
#define L 1024
// triangular decomposition: 16 col-segments of 64; 2 row-bands of 512.
// tiles: band0 q=0..15 (tl=q), band1 q=8..15 (tl=q+8). 24 tiles/batch.
// R16: balanced block mapping — block k<8: tiles {k, 23-k} (k+1 + 8-k = 9
// row-iters); block k>=8: tile {k} (8 iters). 16 blocks/batch, row staged once.
#define NTILE 24
#define TSTRIDE 576   // per-tile ws slice: 512 row partials + 64 col partials

#if __has_builtin(__builtin_amdgcn_exp2f)
#define EXP2(x) __builtin_amdgcn_exp2f(x)
#else
#define EXP2(x) __expf((x) * 0.6931471805599453f)
#endif

typedef unsigned int uint4v __attribute__((ext_vector_type(4)));

// ws layout (floats):
//   [0 .. B*24*576)     per-(b,tile) slices: rows[512] then cols[64]
//   [WS2 .. WS2+B*1024) per-row dcg contributions (written by gather)
//   [WS_ACC]            ndcg accumulator (zeroed by pair_kernel block 0)
//   [WS_GCTR]           completion counter
#define WS2     (B * NTILE * TSTRIDE)
#define WS_ACC  (WS2 + B * L)
#define WS_GCTR (WS_ACC + 1)

// erfc(|y|) ~= exp(-(1.12838 y + 0.6446 y^2 + 0.0745 y^3)), |dPhi| <= ~2.5e-4,
// y = diff/2 (prescaled into the f16 row). Constants pre-multiplied by
// -log2(e) so v_exp_f16 computes exp2 directly.
#define K1f -1.6279072f
#define K2f -0.9299637f
#define K3f -0.1074808f

// one packed evaluation: du holds 2 f16 j-values; returns erf(y_i - y_j) x2
// (signed, via v_bfi sign transfer). d==0 gives exactly 0 (e=1, r=0, +0 sign),
// so diagonal elements self-cancel. Math verified absmax=0.0 (R15/R16 runs).
__device__ __forceinline__ __half2 term2v(unsigned int du, __half2 pi2,
                                          __half2 k1, __half2 k2, __half2 k3,
                                          __half2 one2) {
    __half2 pj = __builtin_bit_cast(__half2, du);
    __half2 d  = __hsub2(pi2, pj);
    unsigned int dbits = __builtin_bit_cast(unsigned int, d);
    __half2 a  = __builtin_bit_cast(__half2, dbits & 0x7fff7fffu); // |d|
    __half2 t  = __hfma2(k3, a, k2);
    __half2 u  = __hfma2(t,  a, k1);
    __half2 w  = __hmul2(a, u);                      // <= 0
    __half2 e  = __halves2half2(hexp2(__low2half(w)),
                                hexp2(__high2half(w)));   // ~= erfc(|y|)
    __half2 r  = __hsub2(one2, e);                   // >= 0, sign bits clear
    unsigned int rs = (dbits & 0x80008000u)
                    | (__builtin_bit_cast(unsigned int, r) & 0x7fff7fffu);
    return __builtin_bit_cast(__half2, rs);          // erf(y), signed
}

// Antisymmetric (triangular) pair kernel, balanced mapping.
// Sub-tiles (seg s in band r) x (seg q): s<q -> row+col accumulate;
// s==q -> full 64x64, ROW-ONLY (diag term = 0); s>q skipped (mirror covered
// by the (q,s) tile's col path). Erf work = 136/256 = 53% of full.
// Col partials: 8 regs/thread across row-iters, reduced once per tile via
// LDS. Plain disjoint ws stores only — no global atomics here (R6 lesson).
__global__ __launch_bounds__(256, 8) void pair_kernel(const float* __restrict__ preds,
                                                      const float* __restrict__ target,
                                                      float* __restrict__ ws) {
    // sph[1024] f16 | rowLDS f32[8][4][64] | colLDS u32[32][64]
    // col2LDS f32[8][64] aliases colLDS's low 2KB (sph must stay live for
    // tile 2; barrier separates the s1 colLDS-read from the col2 store).
    __shared__ __align__(16) unsigned char smem[2048 + 8192 + 8192];
    __half* sph = (__half*)smem;
    float* rowLDS = (float*)(smem + 2048);
    unsigned int* colLDS = (unsigned int*)(smem + 2048 + 8192);
    float* col2LDS = (float*)(smem + 2048 + 8192);   // alias, low 2KB

    const int blk = blockIdx.x;
    const int b   = blk >> 4;
    const int kk  = blk & 15;
    const int tid = threadIdx.x;
    const int il  = tid & 63;
    const int jq  = tid >> 6;

    if (blk == 0 && tid == 0) {
        ws[WS_ACC] = 0.0f;                 // visible to finish at dispatch boundary
        ((int*)ws)[WS_GCTR] = 0;
    }

    // stage full row as f16, prescaled by 0.5 (erf argument is diff/2)
    const float* prow = preds + b * L;
    float4 v4 = reinterpret_cast<const float4*>(prow)[tid];
    reinterpret_cast<__half2*>(sph)[tid * 2 + 0] = __floats2half2_rn(0.5f * v4.x, 0.5f * v4.y);
    reinterpret_cast<__half2*>(sph)[tid * 2 + 1] = __floats2half2_rn(0.5f * v4.z, 0.5f * v4.w);
    __syncthreads();

    const __half2 k1   = __floats2half2_rn(K1f, K1f);
    const __half2 k2   = __floats2half2_rn(K2f, K2f);
    const __half2 k3   = __floats2half2_rn(K3f, K3f);
    const __half2 one2 = __floats2half2_rn(1.0f, 1.0f);
    const __half2 z2   = __floats2half2_rn(0.0f, 0.0f);

    const int ntl = (kk < 8) ? 2 : 1;
    for (int tt = 0; tt < ntl; ++tt) {
        const int tl = tt ? (23 - kk) : kk;
        const int r  = (tl >= 16) ? 1 : 0;
        const int q  = r ? (tl - 8) : tl;

        // this thread's 16 j's of seg q (8 half2)
        const uint4v* cp4 = reinterpret_cast<const uint4v*>(sph + q * 64 + jq * 16);
        uint4v pq0 = cp4[0], pq1 = cp4[1];
        unsigned int pjb[8] = {pq0.x, pq0.y, pq0.z, pq0.w, pq1.x, pq1.y, pq1.z, pq1.w};

        __half2 colacc[8] = {z2, z2, z2, z2, z2, z2, z2, z2};

        const int r8 = r << 3;
        for (int rr = 0; rr < 8; ++rr) {   // rows: seg s = 8r+rr (uniform trip)
            const int s = r8 + rr;
            if (s > q) break;
            const bool ca = (s < q);       // col-accumulate? (uniform)
            const __half2 pi2 = __half2half2(sph[(s << 6) + il]);
            __half2 A = z2, Bc = z2;       // two 4-deep row chains
            #pragma unroll
            for (int m = 0; m < 8; ++m) {
                __half2 tm = term2v(pjb[m], pi2, k1, k2, k3, one2);
                if (m < 4) A = __hadd2(A, tm); else Bc = __hadd2(Bc, tm);
                if (ca) colacc[m] = __hadd2(colacc[m], tm);  // <=8 adds: f16 ok
            }
            float2 fA = __half22float2(A), fB = __half22float2(Bc);
            rowLDS[(rr << 8) + (jq << 6) + il] = (fA.x + fA.y) + (fB.x + fB.y);
        }

        // park col partials (conflict-free per-thread slots)
        #pragma unroll
        for (int m = 0; m < 8; ++m)
            colLDS[((jq << 3) + m) * 64 + il] = __builtin_bit_cast(unsigned int, colacc[m]);
        __syncthreads();

        float* wst = ws + (b * NTILE + tl) * TSTRIDE;

        // row writeout: 2 rows/thread, sum the 4 j-quarters. Slices for rr
        // beyond this tile's trip carry stale/uninit data but are never read
        // by gather (q>=s filter).
        #pragma unroll
        for (int h = 0; h < 2; ++h) {
            int rho = tid + (h << 8);
            int rrx = rho >> 6, ilx = rho & 63;
            float v = (rowLDS[(rrx << 8) + ilx]       + rowLDS[(rrx << 8) + 64 + ilx])
                    + (rowLDS[(rrx << 8) + 128 + ilx] + rowLDS[(rrx << 8) + 192 + ilx]);
            wst[rho] = v;
        }

        // col reduce stage 1: thread (cp=tid&31, ilq=tid>>5) sums 8 lanes'
        // half2 partials in f32 (into regs; store deferred past the barrier
        // because col2 aliases colLDS).
        float sx = 0.0f, sy = 0.0f;
        {
            int cp = tid & 31, ilq = tid >> 5;
            const uint4v* cl = reinterpret_cast<const uint4v*>(colLDS + cp * 64 + ilq * 8);
            uint4v c0 = cl[0], c1 = cl[1];
            unsigned int cc[8] = {c0.x, c0.y, c0.z, c0.w, c1.x, c1.y, c1.z, c1.w};
            #pragma unroll
            for (int m = 0; m < 8; ++m) {
                float2 f = __half22float2(__builtin_bit_cast(__half2, cc[m]));
                sx += f.x; sy += f.y;
            }
        }
        __syncthreads();                   // all colLDS reads done
        {
            int cp = tid & 31, ilq = tid >> 5;
            col2LDS[ilq * 64 + cp * 2 + 0] = sx;   // [ilq][j_local]
            col2LDS[ilq * 64 + cp * 2 + 1] = sy;
        }
        __syncthreads();

        // col reduce stage 2: thread t<64 owns j_local = t
        if (tid < 64) {
            float cs = 0.0f;
            #pragma unroll
            for (int g = 0; g < 8; ++g) cs += col2LDS[g * 64 + tid];
            wst[512 + tid] = cs;
        }
        __syncthreads();                   // protect rowLDS/colLDS for next tile
    }
}

// grid = B*4 = 512 blocks, 256 threads; one row i per thread. Gathers Es from
// the verified slice layout (R16 absmax=0.0 indexing, verbatim), applies the
// DCG tail, writes per-row contrib to ws2. 2 blocks/CU -> 8 waves/CU of
// latency hiding (the 128-block rolled gather was R16's ~15-20us regression).
__global__ __launch_bounds__(256) void gather_kernel(const float* __restrict__ target,
                                                     float* __restrict__ ws) {
    const int blk = blockIdx.x;
    const int b   = blk >> 2;
    const int i   = ((blk & 3) << 8) + threadIdx.x;
    const int u   = i >> 6;            // seg (wave-uniform: i is 64-aligned/wave)
    const int rb  = u >> 3;            // band
    const int rho = i & 511;
    const int i6  = i & 63;
    const int b24 = b * NTILE;

    float rowsum = 0.0f;
    for (int qq = u; qq < 16; ++qq)
        rowsum += ws[(b24 + qq + (rb << 3)) * TSTRIDE + rho];
    float cols = 0.0f;
    if (u >= 1) cols += ws[(b24 + u) * TSTRIDE + 512 + i6];
    if (u >= 9) cols += ws[(b24 + u + 8) * TSTRIDE + 512 + i6];

    float Es  = rowsum - cols;
    float er1 = 513.5f + 0.5f * Es;    // er+1 = 513.5 + Es/2 (diag term = 0)
    float g   = EXP2(target[b * L + i]) - 1.0f;  // 2^t - 1, exact for int grades
    ws[WS2 + b * L + i] = g * __builtin_amdgcn_rcpf(__log2f(er1));
}

// grid = B blocks, 256 threads. Block b: counting-sort IDCG, sum the 1024
// per-row contribs (coalesced), ndcg; last block writes the final scalar.
__global__ __launch_bounds__(256) void finish_kernel(const float* __restrict__ target,
                                                     float* __restrict__ ws,
                                                     float* __restrict__ out) {
    __shared__ unsigned long long cred[256];
    __shared__ float2 fred[256];

    const int b   = blockIdx.x;
    const int tid = threadIdx.x;
    const float* trow = target + b * L;

    // packed 16-bit counts of grades >=4,>=3,>=2,>=1 (max 1024 fits)
    unsigned long long cnt = 0ull;
    #pragma unroll
    for (int k = 0; k < 4; ++k) {
        float t = trow[tid + k * 256];
        cnt += ((unsigned long long)(t > 3.5f) << 48)
             + ((unsigned long long)(t > 2.5f) << 32)
             + ((unsigned long long)(t > 1.5f) << 16)
             + ((unsigned long long)(t > 0.5f));
    }
    cred[tid] = cnt;
    __syncthreads();
    #pragma unroll
    for (int s = 128; s > 0; s >>= 1) {
        if (tid < (unsigned)s) cred[tid] += cred[tid + s];
        __syncthreads();
    }
    unsigned long long tot = cred[0];
    const int n4 = (int)(tot >> 48) & 0xFFFF;
    const int n3 = (int)(tot >> 32) & 0xFFFF;
    const int n2 = (int)(tot >> 16) & 0xFFFF;
    const int n1 = (int)(tot)       & 0xFFFF;

    // parallel IDCG; joint reduction with the per-row dcg contribs
    float idcg_p = 0.0f;
    float dcg_p  = 0.0f;
    #pragma unroll
    for (int k = 0; k < 4; ++k) {
        int pos = tid + 1 + k * 256;
        float gain = (pos <= n4) ? 15.0f : (pos <= n3) ? 7.0f :
                     (pos <= n2) ? 3.0f  : (pos <= n1) ? 1.0f : 0.0f;
        idcg_p += gain * __builtin_amdgcn_rcpf(__log2f((float)pos + 1.0f));
        dcg_p  += ws[WS2 + b * L + tid + k * 256];
    }

    fred[tid] = make_float2(idcg_p, dcg_p);
    __syncthreads();
    #pragma unroll
    for (int s = 128; s > 0; s >>= 1) {
        if (tid < (unsigned)s) {
            float2 x = fred[tid], y = fred[tid + s];
            fred[tid] = make_float2(x.x + y.x, x.y + y.y);
        }
        __syncthreads();
    }

    if (tid == 0) {
        float ndcg = fred[0].y / (fred[0].x + 1e-10f);
        atomicAdd(&ws[WS_ACC], ndcg);
        __threadfence();
        int old = atomicAdd((int*)ws + WS_GCTR, 1);
        if (old == B - 1) {
            float acc = atomicAdd(&ws[WS_ACC], 0.0f);  // coherent read
            out[0] = -acc * (1.0f / (float)B);
        }
    }
}

extern "C" void kernel_launch(void* const* d_in, const int* in_sizes, int n_in,
                              void* d_out, int out_size, void* d_ws, size_t ws_size,
                              hipStream_t stream) {
    const float* preds  = (const float*)d_in[0];
    const float* target = (const float*)d_in[1];
    float* out = (float*)d_out;
    float* ws  = (float*)d_ws;

    pair_kernel<<<B * 16, 256, 0, stream>>>(preds, target, ws);
    gather_kernel<<<B * 4, 256, 0, stream>>>(target, ws);
    finish_kernel<<<B, 256, 0, stream>>>(target, ws, out);
}